// Round 7
// baseline (104.632 us; speedup 1.0000x reference)
//
#include <hip/hip_runtime.h>
#include <math.h>

#define HH 384
#define WW 384
#define HWSZ (HH * WW)          // 147456
#define NPIX (2 * HWSZ)         // 294912
#define KSEL 11
#define PW 394                  // padded width/height (5 halo each side)
#define PP (PW * PW)            // 155236 per batch
#define NP2 (2 * PP)            // 310472 padded pixels
#define PREP_BLOCKS ((NP2 + 255) / 256)   // 1213
#define PREP_WAVES (PREP_BLOCKS * 4)      // 4852
#define SEL_BLOCKS (NPIX / 256)           // 1152 (worst case all unknown)
#define SEL_WAVES (SEL_BLOCKS * 4)        // 4608

// ---- d_ws layout (bytes); harness gives ~256 MiB ----
#define IMG4_OFF 0u
#define APAD_OFF (NP2 * 16u)                       // 4,967,552
#define LIST_OFF (APAD_OFF + NP2 * 4u)             // 6,209,440
#define CNT_OFF  (LIST_OFF + NPIX * 4u + 64u)      // 7,389,152
#define KV_OFF   (CNT_OFF + 64u)
#define DS_OFF   (KV_OFF + PREP_WAVES * 4u + 64u)

__device__ __forceinline__ float fast_sqrtf(float x) {
    float r;
    asm("v_sqrt_f32 %0, %1" : "=v"(r) : "v"(x));
    return r;
}

__device__ __forceinline__ float wave_sum(float v) {
#pragma unroll
    for (int off = 32; off > 0; off >>= 1) v += __shfl_down(v, off, 64);
    return v;
}

// Key: high 20 bits = d^2 (f32 bits truncated), low 12 = pre-quantized
// neighbor alpha. d2 >= 0 so float min/max order == lexicographic.
__device__ __forceinline__ float make_key(const float4 c, const float4 n) {
    const float e0 = c.x - n.x;
    const float e1 = c.y - n.y;
    const float e2 = c.z - n.z;
    float d2 = e0 * e0;
    d2 = __builtin_fmaf(e1, e1, d2);
    d2 = __builtin_fmaf(e2, e2, d2);
    const unsigned bits = (__float_as_uint(d2) & 0xFFFFF000u) | __float_as_uint(n.w);
    return __uint_as_float(bits);
}

// Merge an unsorted pair into sorted-ascending bd[0..10], keep smallest 11.
__device__ __forceinline__ void merge2(float bd[KSEL], float a, float b) {
    const float p0 = fminf(a, b);
    const float p1 = fmaxf(a, b);
    float nb[KSEL];
    nb[0] = fminf(bd[0], p0);
    nb[1] = fminf(fminf(bd[1], fmaxf(bd[0], p0)), p1);
#pragma unroll
    for (int j = 2; j < KSEL; ++j)
        nb[j] = fminf(fminf(bd[j], fmaxf(bd[j - 1], p0)), fmaxf(bd[j - 2], p1));
#pragma unroll
    for (int j = 0; j < KSEL; ++j) bd[j] = nb[j];
}

__device__ __forceinline__ void merge1(float bd[KSEL], float p) {
    float cd = p;
#pragma unroll
    for (int j = 0; j < KSEL; ++j) {
        const float mx = fmaxf(cd, bd[j]);
        bd[j] = fminf(cd, bd[j]);
        cd = mx;
    }
}

__device__ __forceinline__ float acc_ddc(const float bd[KSEL], float ac) {
    float s = 0.f;
#pragma unroll
    for (int j = 0; j < KSEL; ++j) {
        const unsigned kb = __float_as_uint(bd[j]);
        const float d2 = __uint_as_float((kb & 0xFFFFF000u) | 0x800u); // midpoint
        const float ad = __builtin_fmaf((float)(kb & 0xFFFu), -1.0f / 4095.0f, ac);
        s += fabsf(fast_sqrtf(d2) - ad);
    }
    return s;
}

// ---- Kernel 1: build padded packed image + exact-alpha plane, compact the
// unknown-pixel list (wave-aggregated atomic), emit known-L1 partials. ----
__global__ __launch_bounds__(256) void matting_prep(
    const float* __restrict__ alpha,
    const float* __restrict__ trimap,
    const float* __restrict__ image,
    float4* __restrict__ img4,
    float* __restrict__ apad,
    unsigned* __restrict__ list,
    unsigned* __restrict__ counter,
    float* __restrict__ kvPart)
{
    const int t = blockIdx.x * 256 + (int)threadIdx.x;
    const int lane = threadIdx.x & 63;
    const int w = threadIdx.x >> 6;

    bool unk = false;
    float kv = 0.f;
    if (t < NP2) {
        const int bb = t / PP;
        const int r  = t - bb * PP;
        const int py = r / PW;
        const int px = r - py * PW;
        const int y = py - 5, x = px - 5;
        float4 v = make_float4(0.f, 0.f, 0.f, 0.f);
        float a = 0.f;
        if ((unsigned)y < (unsigned)HH && (unsigned)x < (unsigned)WW) {
            const int gi = y * WW + x;
            const float* i0 = image + bb * 3 * HWSZ;
            a = alpha[bb * HWSZ + gi];
            const float tri = trimap[bb * HWSZ + gi];
            v.x = __builtin_fmaf(i0[gi],            0.229f, 0.485f);
            v.y = __builtin_fmaf(i0[HWSZ + gi],     0.224f, 0.456f);
            v.z = __builtin_fmaf(i0[2 * HWSZ + gi], 0.225f, 0.406f);
            v.w = __uint_as_float((unsigned)(a * 4095.0f)); // payload bits
            unk = (tri == 0.5f);
            kv  = unk ? 0.f : fabsf(a - tri);
        }
        img4[t] = v;      // border = zeros == reference's zero pad
        apad[t] = a;
    }

    const unsigned long long m = __ballot(unk);
    const unsigned pc = (unsigned)__popcll(m);
    if (pc) {
        unsigned base = 0;
        if (lane == 0) base = atomicAdd(counter, pc);
        base = (unsigned)__shfl((int)base, 0, 64);
        if (unk)
            list[base + (unsigned)__popcll(m & ((1ull << lane) - 1ull))] = (unsigned)t;
    }
    const float s = wave_sum(kv);
    if (lane == 0) kvPart[blockIdx.x * 4 + w] = s;
}

// ---- Kernel 2: selection over the compacted list, 1 px/lane, 100% fill. ----
__global__ __launch_bounds__(256, 2) void matting_select(
    const float4* __restrict__ img4,
    const float* __restrict__ apad,
    const unsigned* __restrict__ list,
    const unsigned* __restrict__ counter,
    float* __restrict__ dsPart)
{
    const int lane = threadIdx.x & 63;
    const int w = threadIdx.x >> 6;
    const int slice = blockIdx.x * 4 + w;
    const unsigned cnt = *counter;
    const unsigned base = (unsigned)slice * 64u;

    float wdsum = 0.f;
    if (base < cnt) {
        const unsigned i = base + (unsigned)lane;
        const bool act = i < cnt;
        const unsigned pidx = act ? list[i] : 0u;   // 0 = border (all zeros)
        const float4* ctr = img4 + pidx;
        const float4 c4 = *ctr;
        const float ac = apad[pidx];

        float bd[KSEL];
#pragma unroll
        for (int j = 0; j < KSEL; ++j) bd[j] = __uint_as_float(0x7F800000u);

#pragma unroll
        for (int di = 0; di < 11; ++di) {
            const float4* row = ctr + (di - 5) * PW - 5;
#pragma unroll
            for (int h = 0; h < 5; ++h)
                merge2(bd, make_key(c4, row[2 * h]), make_key(c4, row[2 * h + 1]));
            merge1(bd, make_key(c4, row[10]));
        }
        wdsum = act ? acc_ddc(bd, ac) : 0.f;
    }
    const float s = wave_sum(wdsum);
    if (lane == 0) dsPart[slice] = s;   // every wave writes (poison-safe)
}

__global__ __launch_bounds__(256) void matting_finalize(
    const float* __restrict__ kvPart,
    const float* __restrict__ dsPart,
    const unsigned* __restrict__ counter,
    float* __restrict__ out)
{
    float ks = 0.f, ds = 0.f;
    for (int i = threadIdx.x; i < PREP_WAVES; i += 256) ks += kvPart[i];
    for (int i = threadIdx.x; i < SEL_WAVES; i += 256) ds += dsPart[i];
    ks = wave_sum(ks);
    ds = wave_sum(ds);
    __shared__ float sk[4], sd[4];
    const int wid = threadIdx.x >> 6, lane = threadIdx.x & 63;
    if (lane == 0) { sk[wid] = ks; sd[wid] = ds; }
    __syncthreads();
    if (threadIdx.x == 0) {
        const float ksum = sk[0] + sk[1] + sk[2] + sk[3];
        const float dsum = sd[0] + sd[1] + sd[2] + sd[3];
        const unsigned cnt = *counter;
        const float known = (cnt < (unsigned)NPIX) ? ksum * (1.0f / (float)NPIX) : 0.f;
        const float ddc   = (cnt > 0u) ? dsum * (0.1f / ((float)NPIX * (float)KSEL)) : 0.f;
        out[0] = known + ddc;
        out[1] = known;
        out[2] = ddc;
    }
}

extern "C" void kernel_launch(void* const* d_in, const int* in_sizes, int n_in,
                              void* d_out, int out_size, void* d_ws, size_t ws_size,
                              hipStream_t stream) {
    const float* alpha  = (const float*)d_in[0];  // pred_alpha  [2,1,384,384]
    const float* trimap = (const float*)d_in[1];  // gt_trimap   [2,1,384,384]
    const float* image  = (const float*)d_in[2];  // input_image [2,3,384,384]
    float* out = (float*)d_out;

    char* ws = (char*)d_ws;
    float4*   img4    = (float4*)(ws + IMG4_OFF);
    float*    apad    = (float*)(ws + APAD_OFF);
    unsigned* list    = (unsigned*)(ws + LIST_OFF);
    unsigned* counter = (unsigned*)(ws + CNT_OFF);
    float*    kvPart  = (float*)(ws + KV_OFF);
    float*    dsPart  = (float*)(ws + DS_OFF);

    hipMemsetAsync(counter, 0, 4, stream);
    matting_prep<<<PREP_BLOCKS, 256, 0, stream>>>(alpha, trimap, image,
                                                  img4, apad, list, counter, kvPart);
    matting_select<<<SEL_BLOCKS, 256, 0, stream>>>(img4, apad, list, counter, dsPart);
    matting_finalize<<<1, 256, 0, stream>>>(kvPart, dsPart, counter, out);
}

// Round 8
// 30.242 us; speedup vs baseline: 3.4598x; 3.4598x over previous
//
#include <hip/hip_runtime.h>
#include <math.h>

#define HH 384
#define WW 384
#define HWSZ (HH * WW)
#define NPIX (2 * HWSZ)
#define KSEL 11
#define TW 48                  // tile width
#define TH 8                   // tile height
#define PXB (TW * TH)          // 384 px per block
#define NCH (PXB / 64)         // 6 compaction chunks
#define TPW (TW + 10)          // 58
#define TPH (TH + 10)          // 18
#define TILE_N (TPW * TPH)     // 1044 float4 (~16.7 KB)
#define NBX (WW / TW)          // 8
#define NBY (HH / TH)          // 48
#define NBLK (2 * NBX * NBY)   // 768 = exactly 3 blocks/CU
#define NW 4                   // waves per block
#define NGROUP (NBLK * NW)     // 3072 partial groups

__device__ __forceinline__ float fast_sqrtf(float x) {
    float r;
    asm("v_sqrt_f32 %0, %1" : "=v"(r) : "v"(x));
    return r;
}

__device__ __forceinline__ float min3f(float a, float b, float c) {
    float r;
    asm("v_min3_f32 %0, %1, %2, %3" : "=v"(r) : "v"(a), "v"(b), "v"(c));
    return r;
}

__device__ __forceinline__ float wave_sum(float v) {
#pragma unroll
    for (int off = 32; off > 0; off >>= 1) v += __shfl_down(v, off, 64);
    return v;
}

// Key: high 20 bits = d^2 (f32 bits truncated), low 12 = pre-quantized
// neighbor alpha. d2 >= 0 so float min/max order == lexicographic.
__device__ __forceinline__ float make_key(const float4 c, const float4 n) {
    const float e0 = c.x - n.x;
    const float e1 = c.y - n.y;
    const float e2 = c.z - n.z;
    float d2 = e0 * e0;
    d2 = __builtin_fmaf(e1, e1, d2);
    d2 = __builtin_fmaf(e2, e2, d2);
    const unsigned bits = (__float_as_uint(d2) & 0xFFFFF000u) | __float_as_uint(n.w);
    return __uint_as_float(bits);
}

// Merge an unsorted pair into sorted-ascending bd[0..10], keep smallest 11.
__device__ __forceinline__ void merge2(float bd[KSEL], float a, float b) {
    const float p0 = fminf(a, b);
    const float p1 = fmaxf(a, b);
    float nb[KSEL];
    nb[0] = fminf(bd[0], p0);
    nb[1] = min3f(bd[1], fmaxf(bd[0], p0), p1);
#pragma unroll
    for (int j = 2; j < KSEL; ++j)
        nb[j] = min3f(bd[j], fmaxf(bd[j - 1], p0), fmaxf(bd[j - 2], p1));
#pragma unroll
    for (int j = 0; j < KSEL; ++j) bd[j] = nb[j];
}

__device__ __forceinline__ void merge1(float bd[KSEL], float p) {
    float cd = p;
#pragma unroll
    for (int j = 0; j < KSEL; ++j) {
        const float mx = fmaxf(cd, bd[j]);
        bd[j] = fminf(cd, bd[j]);
        cd = mx;
    }
}

// Contribution of one selected key, with exact center alpha ac.
__device__ __forceinline__ float key_f(float key, float ac) {
    const unsigned kb = __float_as_uint(key);
    const float d2 = __uint_as_float((kb & 0xFFFFF000u) | 0x800u); // midpoint
    const float ad = __builtin_fmaf((float)(kb & 0xFFFu), -1.0f / 4095.0f, ac);
    return fabsf(fast_sqrtf(d2) - ad);
}

__global__ __launch_bounds__(256, 3) void matting_main(
    const float* __restrict__ alpha,
    const float* __restrict__ trimap,
    const float* __restrict__ image,
    float* __restrict__ ws)
{
    __shared__ float4 tile[TILE_N];            // denorm rgb + quantized-alpha bits
    __shared__ float aex[PXB];                 // exact alpha per block px
    __shared__ unsigned short list[PXB];       // compacted unknown px
    __shared__ unsigned chCnt[NCH];            // per-chunk unknown counts
    __shared__ unsigned long long chMask[NCH]; // per-chunk ballot masks

    const int bx  = blockIdx.x % NBX;
    const int byy = (blockIdx.x / NBX) % NBY;
    const int b   = blockIdx.x / (NBX * NBY);

    const float* i0 = image + b * 3 * HWSZ;
    const float* i1 = i0 + HWSZ;
    const float* i2 = i1 + HWSZ;
    const float* ap = alpha + b * HWSZ;
    const float* tm = trimap + b * HWSZ;

    const int row0 = byy * TH, col0 = bx * TW;
    const int gy0 = row0 - 5, gx0 = col0 - 5;

    // ---- stage padded denormalized tile (zero pad == reference's unfold pad)
#pragma unroll
    for (int it = 0; it < (TILE_N + 255) / 256; ++it) {
        const int t = it * 256 + (int)threadIdx.x;
        if (t < TILE_N) {
            const int ry = t / TPW, rx = t - ry * TPW;
            const int gy = gy0 + ry, gx = gx0 + rx;
            float4 v = make_float4(0.f, 0.f, 0.f, 0.f);
            if ((unsigned)gy < (unsigned)HH && (unsigned)gx < (unsigned)WW) {
                const int gi = gy * WW + gx;
                v.x = __builtin_fmaf(i0[gi], 0.229f, 0.485f);
                v.y = __builtin_fmaf(i1[gi], 0.224f, 0.456f);
                v.z = __builtin_fmaf(i2[gi], 0.225f, 0.406f);
                v.w = __uint_as_float((unsigned)(ap[gi] * 4095.0f)); // payload
            }
            tile[t] = v;
        }
    }

    // ---- phase 1: per-chunk ballots + known-L1 partials + exact alpha ----
    const int lane = threadIdx.x & 63;
    const int w    = threadIdx.x >> 6;
    float kv = 0.f;
    float kcnt = 0.f, scnt = 0.f;
    for (int c = w; c < NCH; c += NW) {
        const int p = c * 64 + lane;                  // 0..383
        const int r = p / TW, cc = p - r * TW;        // block row/col
        const int gi = (row0 + r) * WW + col0 + cc;
        const float a = ap[gi];
        const float tri = tm[gi];
        aex[p] = a;
        const bool unk = (tri == 0.5f);
        kv += unk ? 0.f : fabsf(a - tri);
        kcnt += unk ? 0.f : 1.f;
        scnt += unk ? 1.f : 0.f;
        const unsigned long long m = __ballot(unk);
        if (lane == 0) { chCnt[c] = (unsigned)__popcll(m); chMask[c] = m; }
    }
    __syncthreads();

    // ---- phase 2: deterministic scatter (prefix over chunk counts) ----
    unsigned cntT = 0;
    {
        unsigned pre[NCH + 1];
        pre[0] = 0;
#pragma unroll
        for (int c = 0; c < NCH; ++c) pre[c + 1] = pre[c] + chCnt[c];
        cntT = pre[NCH];
        for (int c = w; c < NCH; c += NW) {
            const unsigned long long m = chMask[c];
            const bool unk = (m >> lane) & 1ull;
            if (unk) {
                const int p = c * 64 + lane;
                list[pre[c] + (unsigned)__popcll(m & ((1ull << lane) - 1ull))] =
                    (unsigned short)p;
            }
        }
    }
    __syncthreads();

    // ---- selection rounds over the block-compacted pool ----
    float wdsum = 0.f;
    for (unsigned base = (unsigned)w * 64u; base < cntT; base += (unsigned)NW * 64u) {
        const unsigned i = base + (unsigned)lane;
        const bool act = i < cntT;
        const unsigned e = act ? (unsigned)list[i] : 0u;
        const int r = (int)(e / TW), cc = (int)(e - (unsigned)r * TW);

        const float4* tp = &tile[r * TPW + cc];   // window (di,dj) at tp[di*TPW+dj]
        const float4 c4 = tp[5 * TPW + 5];
        const float ac = aex[e];

        // dual independent chains: A = window rows 0..4, B = rows 5..10
        float A[KSEL], B[KSEL];
#pragma unroll
        for (int j = 0; j < KSEL; ++j) {
            A[j] = __uint_as_float(0x7F800000u);
            B[j] = __uint_as_float(0x7F800000u);
        }
#pragma unroll
        for (int di = 0; di < 5; ++di) {
            const float4* row = tp + di * TPW;
            const float4* row2 = tp + (di + 5) * TPW;
#pragma unroll
            for (int h = 0; h < 5; ++h) {
                merge2(A, make_key(c4, row[2 * h]), make_key(c4, row[2 * h + 1]));
                merge2(B, make_key(c4, row2[2 * h]), make_key(c4, row2[2 * h + 1]));
            }
            merge1(A, make_key(c4, row[10]));
            merge1(B, make_key(c4, row2[10]));
        }
        {   // B also covers row 10
            const float4* row2 = tp + 10 * TPW;
#pragma unroll
            for (int h = 0; h < 5; ++h)
                merge2(B, make_key(c4, row2[2 * h]), make_key(c4, row2[2 * h + 1]));
            merge1(B, make_key(c4, row2[10]));
        }

        // merge-path recombine: A[i] in union-top-11 iff A[i] <= B[10-i];
        // B[l] iff B[l] < A[10-l]. Ties -> A (lower flat index), and tied
        // keys are bit-identical so the selected-set sum is exact.
        float s = 0.f;
#pragma unroll
        for (int j = 0; j < KSEL; ++j) {
            s += (A[j] <= B[KSEL - 1 - j]) ? key_f(A[j], ac) : 0.f;
            s += (B[j] <  A[KSEL - 1 - j]) ? key_f(B[j], ac) : 0.f;
        }
        wdsum += act ? s : 0.f;
    }

    // ---- per-wave partials ----
    const float vkv = wave_sum(kv);
    const float vkc = wave_sum(kcnt);
    const float vds = wave_sum(wdsum);
    const float vsc = wave_sum(scnt);
    if (lane == 0) {
        float* g = ws + (blockIdx.x * NW + w) * 4;
        g[0] = vkv; g[1] = vkc; g[2] = vds; g[3] = vsc;
    }
}

__global__ __launch_bounds__(256) void matting_finalize(
    const float* __restrict__ ws, float* __restrict__ out)
{
    float a = 0, b = 0, c = 0, d = 0;
    for (int i = threadIdx.x; i < NGROUP; i += 256) {
        a += ws[i * 4 + 0];
        b += ws[i * 4 + 1];
        c += ws[i * 4 + 2];
        d += ws[i * 4 + 3];
    }
    a = wave_sum(a); b = wave_sum(b); c = wave_sum(c); d = wave_sum(d);
    __shared__ float sred[4][4];
    const int wid = threadIdx.x >> 6, lane = threadIdx.x & 63;
    if (lane == 0) { sred[wid][0] = a; sred[wid][1] = b; sred[wid][2] = c; sred[wid][3] = d; }
    __syncthreads();
    if (threadIdx.x == 0) {
        float ksum = 0, kcnt = 0, dsum = 0, scnt = 0;
#pragma unroll
        for (int q = 0; q < 4; ++q) {
            ksum += sred[q][0]; kcnt += sred[q][1]; dsum += sred[q][2]; scnt += sred[q][3];
        }
        const float known = (kcnt > 0.f) ? ksum * (1.0f / (float)NPIX) : 0.f;
        const float ddc   = (scnt > 0.f) ? dsum * (0.1f / ((float)NPIX * (float)KSEL)) : 0.f;
        out[0] = known + ddc;
        out[1] = known;
        out[2] = ddc;
    }
}

extern "C" void kernel_launch(void* const* d_in, const int* in_sizes, int n_in,
                              void* d_out, int out_size, void* d_ws, size_t ws_size,
                              hipStream_t stream) {
    const float* alpha  = (const float*)d_in[0];  // pred_alpha  [2,1,384,384]
    const float* trimap = (const float*)d_in[1];  // gt_trimap   [2,1,384,384]
    const float* image  = (const float*)d_in[2];  // input_image [2,3,384,384]
    float* out = (float*)d_out;
    float* ws  = (float*)d_ws;                    // NGROUP*4 floats

    matting_main<<<NBLK, 256, 0, stream>>>(alpha, trimap, image, ws);
    matting_finalize<<<1, 256, 0, stream>>>(ws, out);
}

// Round 9
// 27.790 us; speedup vs baseline: 3.7651x; 1.0883x over previous
//
#include <hip/hip_runtime.h>
#include <math.h>

#define HH 384
#define WW 384
#define HWSZ (HH * WW)
#define NPIX (2 * HWSZ)
#define KSEL 11
#define TW 48                  // tile width
#define TH 12                  // tile height (4 waves x 3 rows)
#define TPW (TW + 10)          // 58
#define TPH (TH + 10)          // 22
#define TILE_N (TPW * TPH)     // 1276 float4 (~20.4 KB)
#define NBX (WW / TW)          // 8
#define NBY (HH / TH)          // 32
#define NBLK (2 * NBX * NBY)   // 512 = exactly 2 blocks/CU
#define NW 4                   // waves per block
#define RPW 3                  // rows per wave
#define PXW (TW * RPW)         // 144 px per wave
#define NGROUP (NBLK * NW)     // 2048 partial groups

__device__ __forceinline__ float fast_sqrtf(float x) {
    float r;
    asm("v_sqrt_f32 %0, %1" : "=v"(r) : "v"(x));
    return r;
}

__device__ __forceinline__ float wave_sum(float v) {
#pragma unroll
    for (int off = 32; off > 0; off >>= 1) v += __shfl_down(v, off, 64);
    return v;
}

// Key: high 20 bits = d^2 (f32 bits truncated), low 12 = pre-quantized
// neighbor alpha. d2 >= 0 so float min/max order == lexicographic.
__device__ __forceinline__ float make_key(const float4 c, const float4 n) {
    const float e0 = c.x - n.x;
    const float e1 = c.y - n.y;
    const float e2 = c.z - n.z;
    float d2 = e0 * e0;
    d2 = __builtin_fmaf(e1, e1, d2);
    d2 = __builtin_fmaf(e2, e2, d2);
    const unsigned bits = (__float_as_uint(d2) & 0xFFFFF000u) | __float_as_uint(n.w);
    return __uint_as_float(bits);
}

// Merge an unsorted pair into sorted-ascending bd[0..10], keep smallest 11.
// Nested fminf/fmaxf (fuses to v_min3/v_max3, keeps scheduler freedom).
__device__ __forceinline__ void merge2(float bd[KSEL], float a, float b) {
    const float p0 = fminf(a, b);
    const float p1 = fmaxf(a, b);
    float nb[KSEL];
    nb[0] = fminf(bd[0], p0);
    nb[1] = fminf(fminf(bd[1], fmaxf(bd[0], p0)), p1);
#pragma unroll
    for (int j = 2; j < KSEL; ++j)
        nb[j] = fminf(fminf(bd[j], fmaxf(bd[j - 1], p0)), fmaxf(bd[j - 2], p1));
#pragma unroll
    for (int j = 0; j < KSEL; ++j) bd[j] = nb[j];
}

__device__ __forceinline__ void merge1(float bd[KSEL], float p) {
    float cd = p;
#pragma unroll
    for (int j = 0; j < KSEL; ++j) {
        const float mx = fmaxf(cd, bd[j]);
        bd[j] = fminf(cd, bd[j]);
        cd = mx;
    }
}

__device__ __forceinline__ float acc_ddc(const float bd[KSEL], float ac) {
    float s = 0.f;
#pragma unroll
    for (int j = 0; j < KSEL; ++j) {
        const unsigned kb = __float_as_uint(bd[j]);
        const float d2 = __uint_as_float((kb & 0xFFFFF000u) | 0x800u); // midpoint
        const float ad = __builtin_fmaf((float)(kb & 0xFFFu), -1.0f / 4095.0f, ac);
        s += fabsf(fast_sqrtf(d2) - ad);
    }
    return s;
}

// Software-pipelined row helpers (all offsets are compile-time -> fold into
// the ds_read offset immediate; loads for row di+1 issue before row di's math).
#define LOAD_ROW(DST, DI)                                   \
    _Pragma("unroll") for (int h_ = 0; h_ < 11; ++h_)       \
        DST[h_] = tp[(DI) * TPW + h_];

#define PROC_ROW(SRC)                                       \
    {                                                       \
        float k_[11];                                       \
        _Pragma("unroll") for (int h_ = 0; h_ < 11; ++h_)   \
            k_[h_] = make_key(c4, SRC[h_]);                 \
        _Pragma("unroll") for (int h_ = 0; h_ < 5; ++h_)    \
            merge2(bd, k_[2 * h_], k_[2 * h_ + 1]);         \
        merge1(bd, k_[10]);                                 \
    }

__global__ __launch_bounds__(256, 2) void matting_main(
    const float* __restrict__ alpha,
    const float* __restrict__ trimap,
    const float* __restrict__ image,
    float* __restrict__ ws)
{
    __shared__ float4 tile[TILE_N];          // denorm rgb + quantized-alpha bits
    __shared__ float aex[TH * TW];           // exact alpha, block-interior px
    __shared__ unsigned short list[NW][PXW]; // compacted unknown px per wave

    const int bx  = blockIdx.x % NBX;
    const int byy = (blockIdx.x / NBX) % NBY;
    const int b   = blockIdx.x / (NBX * NBY);

    const float* i0 = image + b * 3 * HWSZ;
    const float* i1 = i0 + HWSZ;
    const float* i2 = i1 + HWSZ;
    const float* ap = alpha + b * HWSZ;
    const float* tm = trimap + b * HWSZ;

    const int row0 = byy * TH, col0 = bx * TW;
    const int gy0 = row0 - 5, gx0 = col0 - 5;

    // ---- stage padded denormalized tile (zero pad == reference's unfold pad)
#pragma unroll
    for (int it = 0; it < (TILE_N + 255) / 256; ++it) {
        const int t = it * 256 + (int)threadIdx.x;
        if (t < TILE_N) {
            const int ry = t / TPW, rx = t - ry * TPW;
            const int gy = gy0 + ry, gx = gx0 + rx;
            float4 v = make_float4(0.f, 0.f, 0.f, 0.f);
            if ((unsigned)gy < (unsigned)HH && (unsigned)gx < (unsigned)WW) {
                const int gi = gy * WW + gx;
                v.x = __builtin_fmaf(i0[gi], 0.229f, 0.485f);
                v.y = __builtin_fmaf(i1[gi], 0.224f, 0.456f);
                v.z = __builtin_fmaf(i2[gi], 0.225f, 0.406f);
                v.w = __uint_as_float((unsigned)(ap[gi] * 4095.0f)); // payload
            }
            tile[t] = v;
        }
    }

    // ---- per-wave compaction of unknown px + known-L1 partials ----
    const int lane = threadIdx.x & 63;
    const int w    = threadIdx.x >> 6;
    unsigned cnt = 0;
    float kv = 0.f;
#pragma unroll
    for (int ch = 0; ch < 3; ++ch) {
        const int p = ch * 64 + lane;            // 0..191, valid < 144
        const bool in = p < PXW;
        const int rl = p / TW, cc = p - rl * TW; // row-in-wave 0..2, col 0..47
        const int rb = w * RPW + rl;             // block-local row 0..11
        float a = 0.f, tri = 1.f;
        if (in) {
            const int gi = (row0 + rb) * WW + col0 + cc;
            a = ap[gi];
            tri = tm[gi];
            aex[rb * TW + cc] = a;               // exact center alpha
        }
        const bool unk = in && (tri == 0.5f);
        kv += (in && tri != 0.5f) ? fabsf(a - tri) : 0.f;
        const unsigned long long m = __ballot(unk);
        if (unk)
            list[w][cnt + (unsigned)__popcll(m & ((1ull << lane) - 1ull))] =
                (unsigned short)((rb << 6) | cc);
        cnt += (unsigned)__popcll(m);
    }
    cnt = (unsigned)__builtin_amdgcn_readfirstlane((int)cnt);

    __syncthreads();

    // ---- selection rounds over compacted unknown pixels ----
    float wdsum = 0.f;
    for (unsigned start = 0; start < cnt; start += 64) {
        const unsigned i = start + (unsigned)lane;
        const bool act = i < cnt;
        if (act) {   // exec-masked: inactive lanes issue no LDS traffic
            const unsigned e = (unsigned)list[w][i];
            const int r = (int)(e >> 6), cc = (int)(e & 63u);

            const float4* tp = &tile[r * TPW + cc];
            const float4 c4 = tp[5 * TPW + 5];
            const float ac = aex[r * TW + cc];

            float bd[KSEL];
#pragma unroll
            for (int j = 0; j < KSEL; ++j) bd[j] = __uint_as_float(0x7F800000u);

            // double-buffered row pipeline: loads for row di+1 in flight
            // while row di's keys+merges execute.
            float4 A_[11], B_[11];
            LOAD_ROW(A_, 0)
            LOAD_ROW(B_, 1)
#pragma unroll
            for (int dd = 0; dd < 5; ++dd) {
                PROC_ROW(A_)
                if (2 * dd + 2 < 11) LOAD_ROW(A_, 2 * dd + 2)
                PROC_ROW(B_)
                if (2 * dd + 3 < 11) LOAD_ROW(B_, 2 * dd + 3)
            }
            PROC_ROW(A_)   // row 10

            wdsum += acc_ddc(bd, ac);
        }
    }

    // ---- per-wave partials ----
    const float vkv = wave_sum(kv);
    const float vds = wave_sum(wdsum);
    if (lane == 0) {
        float* g = ws + (blockIdx.x * NW + w) * 4;
        g[0] = vkv;
        g[1] = (float)(PXW - (int)cnt);   // known count
        g[2] = vds;
        g[3] = (float)cnt;                // sample (unknown) count
    }
}

__global__ __launch_bounds__(256) void matting_finalize(
    const float* __restrict__ ws, float* __restrict__ out)
{
    float a = 0, b = 0, c = 0, d = 0;
    for (int i = threadIdx.x; i < NGROUP; i += 256) {
        a += ws[i * 4 + 0];
        b += ws[i * 4 + 1];
        c += ws[i * 4 + 2];
        d += ws[i * 4 + 3];
    }
    a = wave_sum(a); b = wave_sum(b); c = wave_sum(c); d = wave_sum(d);
    __shared__ float sred[4][4];
    const int wid = threadIdx.x >> 6, lane = threadIdx.x & 63;
    if (lane == 0) { sred[wid][0] = a; sred[wid][1] = b; sred[wid][2] = c; sred[wid][3] = d; }
    __syncthreads();
    if (threadIdx.x == 0) {
        float ksum = 0, kcnt = 0, dsum = 0, scnt = 0;
#pragma unroll
        for (int q = 0; q < 4; ++q) {
            ksum += sred[q][0]; kcnt += sred[q][1]; dsum += sred[q][2]; scnt += sred[q][3];
        }
        const float known = (kcnt > 0.f) ? ksum * (1.0f / (float)NPIX) : 0.f;
        const float ddc   = (scnt > 0.f) ? dsum * (0.1f / ((float)NPIX * (float)KSEL)) : 0.f;
        out[0] = known + ddc;
        out[1] = known;
        out[2] = ddc;
    }
}

extern "C" void kernel_launch(void* const* d_in, const int* in_sizes, int n_in,
                              void* d_out, int out_size, void* d_ws, size_t ws_size,
                              hipStream_t stream) {
    const float* alpha  = (const float*)d_in[0];  // pred_alpha  [2,1,384,384]
    const float* trimap = (const float*)d_in[1];  // gt_trimap   [2,1,384,384]
    const float* image  = (const float*)d_in[2];  // input_image [2,3,384,384]
    float* out = (float*)d_out;
    float* ws  = (float*)d_ws;                    // NGROUP*4 floats

    matting_main<<<NBLK, 256, 0, stream>>>(alpha, trimap, image, ws);
    matting_finalize<<<1, 256, 0, stream>>>(ws, out);
}